// Round 1
// baseline (97.371 us; speedup 1.0000x reference)
//
#include <hip/hip_runtime.h>

// Problem constants (fixed by the reference).
constexpr int B = 2, S = 4096, H = 16, D = 128;
constexpr int MAXSEQ = 4096;
constexpr int HD = H * D;                         // 2048 floats per row
constexpr int NBS = B * S;                        // 8192 (k/v rows)
constexpr int NCACHE = B * MAXSEQ;                // 8192 (cache rows)
constexpr long long NK = (long long)NBS * HD;     // 16,777,216 floats per tensor
constexpr long long NK4 = NK / 4;                 // in float4 units
constexpr int VR = HD / 4;                        // 512 float4 per row

// Prep kernel: single block.
//  - detects whether update_mask arrived as int32 or uint8
//  - builds sel[t]   (t in [0,NBS)):   cache row to gather from, or -1 (use k/v row t)
//  - builds inv[c]   (c in [0,NCACHE)): k/v row scattered into cache row c, or -1 (keep old)
//  - computes hit_rate, new_valid_length, num_updates and writes them (as floats)
__global__ __launch_bounds__(1024) void prep_kernel(
    const int* __restrict__ pos, const void* __restrict__ um_raw,
    const int* __restrict__ cvl_p,
    int* __restrict__ sel, int* __restrict__ inv,
    float* __restrict__ scalars)
{
    const int tid = threadIdx.x;
    __shared__ int s_flag;
    if (tid == 0) s_flag = 0;
    __syncthreads();

    // dtype detection: int32 view of a bool(1B) bernoulli buffer has values >1
    {
        const int* mi = (const int*)um_raw;
        int bad = 0;
        for (int i = tid; i < NBS / 4; i += 1024)
            if ((unsigned)mi[i] > 1u) bad = 1;
        if (bad) atomicOr(&s_flag, 1);
    }
    // init inverse map
    for (int i = tid; i < NCACHE; i += 1024) inv[i] = -1;
    __syncthreads();

    const int is_u8 = s_flag;
    const int cvl = cvl_p[0];
    const unsigned char* m8 = (const unsigned char*)um_raw;
    const int* m32 = (const int*)um_raw;

    int hits = 0, upd = 0, anyu = 0;
    int maxp = -2147483647 - 1;
    for (int i = tid; i < NBS; i += 1024) {
        int p = pos[i];
        int um = is_u8 ? (m8[i] != 0) : (m32[i] != 0);
        int b = i / S;
        hits += (p < cvl) ? 1 : 0;
        upd += um;
        anyu |= um;
        maxp = p > maxp ? p : maxp;
        int gm = (p < cvl) && !um;                  // gather path
        sel[i] = gm ? (b * MAXSEQ + p) : -1;
        if (um && p >= 0 && p < MAXSEQ)             // scatter path (OOB dropped)
            inv[b * MAXSEQ + p] = i;                // positions distinct per batch row
    }

    // block reduction (16 waves of 64)
    for (int off = 32; off; off >>= 1) {
        hits += __shfl_down(hits, off);
        upd  += __shfl_down(upd, off);
        anyu |= __shfl_down(anyu, off);
        int o = __shfl_down(maxp, off);
        maxp = o > maxp ? o : maxp;
    }
    __shared__ int sh[16][4];
    const int wid = tid >> 6, lane = tid & 63;
    if (lane == 0) { sh[wid][0] = hits; sh[wid][1] = upd; sh[wid][2] = maxp; sh[wid][3] = anyu; }
    __syncthreads();
    if (tid == 0) {
        int h = 0, u = 0, mp = -2147483647 - 1, au = 0;
        for (int w = 0; w < 16; ++w) {
            h += sh[w][0]; u += sh[w][1];
            mp = sh[w][2] > mp ? sh[w][2] : mp;
            au |= sh[w][3];
        }
        float ema_h = 0.01f * (float)h;
        float ema_m = 0.01f * ((float)NBS - (float)h);
        scalars[0] = ema_h / (ema_h + ema_m + 1e-8f);     // hit_rate
        int nvl_hi = cvl > (mp + 1) ? cvl : (mp + 1);
        int nvl = au ? (nvl_hi < MAXSEQ ? nvl_hi : MAXSEQ) : cvl;
        scalars[1] = (float)nvl;                          // new_valid_length
        scalars[2] = (float)u;                            // num_updates
    }
}

// One block per output row (k_out/v_out rows first, then cache rows).
// Each block copies one 8KB K row and one 8KB V row, fully coalesced float4.
__global__ __launch_bounds__(256) void copy_kernel(
    const float4* __restrict__ k, const float4* __restrict__ v,
    const float4* __restrict__ ck, const float4* __restrict__ cv,
    const int* __restrict__ sel, const int* __restrict__ inv,
    float4* __restrict__ out)
{
    const int t = blockIdx.x;
    const int tid = threadIdx.x;
    const float4 *srcK, *srcV;
    float4 *dstK, *dstV;

    if (t < NBS) {                       // k_out / v_out rows
        const int g = sel[t];
        const long long row = (long long)t * VR;
        if (g >= 0) {
            const long long gr = (long long)g * VR;
            srcK = ck + gr; srcV = cv + gr;
        } else {
            srcK = k + row; srcV = v + row;
        }
        dstK = out + row;                // k_out
        dstV = out + NK4 + row;          // v_out
    } else {                             // new_cached_k / new_cached_v rows
        const int c = t - NBS;
        const int s = inv[c];
        const long long crow = (long long)c * VR;
        if (s >= 0) {
            const long long sr = (long long)s * VR;
            srcK = k + sr; srcV = v + sr;
        } else {
            srcK = ck + crow; srcV = cv + crow;
        }
        dstK = out + 2 * NK4 + crow;     // new_cached_k
        dstV = out + 3 * NK4 + crow;     // new_cached_v
    }

    #pragma unroll
    for (int i = tid; i < VR; i += 256) {
        dstK[i] = srcK[i];
        dstV[i] = srcV[i];
    }
}

extern "C" void kernel_launch(void* const* d_in, const int* in_sizes, int n_in,
                              void* d_out, int out_size, void* d_ws, size_t ws_size,
                              hipStream_t stream) {
    const float* k  = (const float*)d_in[0];
    const float* v  = (const float*)d_in[1];
    const float* ck = (const float*)d_in[2];
    const float* cv = (const float*)d_in[3];
    const int* pos  = (const int*)d_in[4];
    const void* um  = d_in[5];
    const int* cvl  = (const int*)d_in[6];
    float* out = (float*)d_out;

    int* sel = (int*)d_ws;        // NBS ints
    int* inv = sel + NBS;         // NCACHE ints

    prep_kernel<<<1, 1024, 0, stream>>>(pos, um, cvl, sel, inv, out + 4 * NK);
    copy_kernel<<<NBS + NCACHE, 256, 0, stream>>>(
        (const float4*)k, (const float4*)v, (const float4*)ck, (const float4*)cv,
        sel, inv, (float4*)out);
}

// Round 3
// 92.844 us; speedup vs baseline: 1.0488x; 1.0488x over previous
//
#include <hip/hip_runtime.h>

// Problem constants (fixed by the reference).
constexpr int B = 2, S = 4096, H = 16, D = 128;
constexpr int MAXSEQ = 4096;
constexpr int HD = H * D;                         // 2048 floats per row
constexpr int NBS = B * S;                        // 8192 (k/v rows)
constexpr int NCACHE = B * MAXSEQ;                // 8192 (cache rows)
constexpr long long NK = (long long)NBS * HD;     // 16,777,216 floats per tensor
constexpr long long NK4 = NK / 4;                 // in float4 units
constexpr int VR = HD / 4;                        // 512 float4 per row
constexpr int PREP_BLOCKS = 64;

// Clang-native 16B vector (HIP float4 is a class type the nontemporal
// builtins reject).
typedef float vf4 __attribute__((ext_vector_type(4)));

// ws layout: inv[NCACHE] ints, then cnt[8] ints
// cnt: 0=hits, 1=num_updates, 2=any_update, 3=max_pos, 4=is_u8 flag

// Init: inv = -1 everywhere; block 0 additionally zeroes counters and
// detects update_mask dtype (int32 0/1 vs packed 1-byte bools: the int32
// view of byte-bools contains values >1 with overwhelming probability).
__global__ __launch_bounds__(256) void init_kernel(
    int* __restrict__ inv, int* __restrict__ cnt, const void* __restrict__ um_raw)
{
    const int i = blockIdx.x * 256 + threadIdx.x;
    if (i < NCACHE) inv[i] = -1;
    if (blockIdx.x == 0) {
        if (threadIdx.x == 0) {
            cnt[0] = 0; cnt[1] = 0; cnt[2] = 0; cnt[3] = -2147483647 - 1; cnt[4] = 0;
        }
        __syncthreads();
        const int* mi = (const int*)um_raw;
        int bad = 0;
        for (int j = threadIdx.x; j < NBS / 4; j += 256)
            if ((unsigned)mi[j] > 1u) bad = 1;
        for (int off = 32; off; off >>= 1) bad |= __shfl_down(bad, off);
        if ((threadIdx.x & 63) == 0 && bad) atomicOr(&cnt[4], 1);
    }
}

// Parallel prep: build inverse scatter map + scalar stats via atomics.
// Positions are distinct per batch row, so inv writes are conflict-free.
__global__ __launch_bounds__(256) void prep_kernel(
    const int* __restrict__ pos, const void* __restrict__ um_raw,
    const int* __restrict__ cvl_p, int* __restrict__ inv, int* __restrict__ cnt)
{
    const int is_u8 = cnt[4];
    const int cvl = cvl_p[0];
    const unsigned char* m8 = (const unsigned char*)um_raw;
    const int* m32 = (const int*)um_raw;

    int hits = 0, upd = 0, anyu = 0;
    int maxp = -2147483647 - 1;
    for (int i = blockIdx.x * 256 + threadIdx.x; i < NBS; i += 256 * PREP_BLOCKS) {
        const int p = pos[i];
        const int um = is_u8 ? (m8[i] != 0) : (m32[i] != 0);
        const int b = i >> 12;                       // i / S, S = 4096
        hits += (p < cvl) ? 1 : 0;
        upd += um;
        anyu |= um;
        maxp = p > maxp ? p : maxp;
        if (um && (unsigned)p < (unsigned)MAXSEQ)
            inv[b * MAXSEQ + p] = i;
    }
    for (int off = 32; off; off >>= 1) {
        hits += __shfl_down(hits, off);
        upd  += __shfl_down(upd, off);
        anyu |= __shfl_down(anyu, off);
        int o = __shfl_down(maxp, off);
        maxp = o > maxp ? o : maxp;
    }
    if ((threadIdx.x & 63) == 0) {
        atomicAdd(&cnt[0], hits);
        atomicAdd(&cnt[1], upd);
        atomicOr(&cnt[2], anyu);
        atomicMax(&cnt[3], maxp);
    }
}

// Main kernel: one block per output row.
//  blocks [0, NBS):        k_out/v_out row t; if scattered, also writes the
//                          cache destination row (k/v row read exactly once).
//  blocks [NBS, NBS+NCACHE): cache row c copied only if not scattered into.
// Block 0 thread 0 finalizes the three scalar outputs.
__global__ __launch_bounds__(256) void main_kernel(
    const vf4* __restrict__ k, const vf4* __restrict__ v,
    const vf4* __restrict__ ck, const vf4* __restrict__ cv,
    const int* __restrict__ pos, const void* __restrict__ um_raw,
    const int* __restrict__ cvl_p, const int* __restrict__ inv,
    const int* __restrict__ cnt, vf4* __restrict__ out,
    float* __restrict__ scalars)
{
    const int t = blockIdx.x;
    const int tid = threadIdx.x;

    if (t == 0 && tid == 0) {
        const int h = cnt[0], u = cnt[1], au = cnt[2], mp = cnt[3];
        const float ema_h = 0.01f * (float)h;
        const float ema_m = 0.01f * ((float)NBS - (float)h);
        scalars[0] = ema_h / (ema_h + ema_m + 1e-8f);
        const int cvl = cvl_p[0];
        int hi = cvl > (mp + 1) ? cvl : (mp + 1);
        if (hi > MAXSEQ) hi = MAXSEQ;
        scalars[1] = (float)(au ? hi : cvl);
        scalars[2] = (float)u;
    }

    if (t < NBS) {
        const int p = pos[t];
        const int is_u8 = cnt[4];
        const int um = is_u8 ? (((const unsigned char*)um_raw)[t] != 0)
                             : (((const int*)um_raw)[t] != 0);
        const int cvl = cvl_p[0];
        const int b = t >> 12;
        const bool gather = (p < cvl) && !um;
        const bool scat = um && ((unsigned)p < (unsigned)MAXSEQ);
        const long long row = (long long)t * VR;
        const int pc = ((unsigned)p < (unsigned)MAXSEQ) ? p : 0;   // safe index
        const long long crow = (long long)(b * MAXSEQ + pc) * VR;

        const vf4* sK = gather ? (ck + crow) : (k + row);
        const vf4* sV = gather ? (cv + crow) : (v + row);
        vf4* dK = out + row;                   // k_out
        vf4* dV = out + NK4 + row;             // v_out
        vf4* cK = out + 2 * NK4 + crow;        // new_cached_k dest
        vf4* cV = out + 3 * NK4 + crow;        // new_cached_v dest

        #pragma unroll
        for (int i = tid; i < VR; i += 256) {
            const vf4 a  = sK[i];
            const vf4 bb = sV[i];
            __builtin_nontemporal_store(a,  &dK[i]);
            __builtin_nontemporal_store(bb, &dV[i]);
            if (scat) {
                __builtin_nontemporal_store(a,  &cK[i]);
                __builtin_nontemporal_store(bb, &cV[i]);
            }
        }
    } else {
        const int c = t - NBS;
        if (inv[c] >= 0) return;                  // scattered: written by k-block
        const long long crow = (long long)c * VR;
        const vf4* sK = ck + crow;
        const vf4* sV = cv + crow;
        vf4* dK = out + 2 * NK4 + crow;
        vf4* dV = out + 3 * NK4 + crow;
        #pragma unroll
        for (int i = tid; i < VR; i += 256) {
            __builtin_nontemporal_store(sK[i], &dK[i]);
            __builtin_nontemporal_store(sV[i], &dV[i]);
        }
    }
}

extern "C" void kernel_launch(void* const* d_in, const int* in_sizes, int n_in,
                              void* d_out, int out_size, void* d_ws, size_t ws_size,
                              hipStream_t stream) {
    const float* k  = (const float*)d_in[0];
    const float* v  = (const float*)d_in[1];
    const float* ck = (const float*)d_in[2];
    const float* cv = (const float*)d_in[3];
    const int* pos  = (const int*)d_in[4];
    const void* um  = d_in[5];
    const int* cvl  = (const int*)d_in[6];
    float* out = (float*)d_out;

    int* inv = (int*)d_ws;          // NCACHE ints
    int* cnt = inv + NCACHE;        // 8 ints

    init_kernel<<<(NCACHE + 255) / 256, 256, 0, stream>>>(inv, cnt, um);
    prep_kernel<<<PREP_BLOCKS, 256, 0, stream>>>(pos, um, cvl, inv, cnt);
    main_kernel<<<NBS + NCACHE, 256, 0, stream>>>(
        (const vf4*)k, (const vf4*)v, (const vf4*)ck, (const vf4*)cv,
        pos, um, cvl, inv, cnt, (vf4*)out, out + 4 * NK);
}

// Round 4
// 88.345 us; speedup vs baseline: 1.1022x; 1.0509x over previous
//
#include <hip/hip_runtime.h>

// Problem constants (fixed by the reference).
constexpr int B = 2, S = 4096, H = 16, D = 128;
constexpr int MAXSEQ = 4096;
constexpr int HD = H * D;                         // 2048 floats per row
constexpr int NBS = B * S;                        // 8192 (k/v rows)
constexpr int NCACHE = B * MAXSEQ;                // 8192 (cache rows)
constexpr long long NK = (long long)NBS * HD;     // 16,777,216 floats per tensor
constexpr long long NK4 = NK / 4;                 // in float4 units
constexpr int VR = HD / 4;                        // 512 float4 per row
constexpr int PREP_BLOCKS = 64;
static_assert(MAXSEQ == S && NBS == NCACHE, "row<->cache-row pairing requires this");

// Clang-native 16B vector (HIP float4 is a class the nontemporal builtins reject).
typedef float vf4 __attribute__((ext_vector_type(4)));

// ws layout (all zeroed by one memset node each call):
//   inv[NCACHE] : t+1 of the k/v row scattered into cache row c, or 0 (keep old)
//   cnt[8]      : 0=hits 1=num_updates 2=any_update 3=max(max_pos+1,0) 4=is_u8

// Parallel prep: dtype-detect, build inverse scatter map, scalar stats.
// Positions are distinct per batch row, so inv writes are conflict-free.
__global__ __launch_bounds__(256) void prep_kernel(
    const int* __restrict__ pos, const void* __restrict__ um_raw,
    const int* __restrict__ cvl_p, int* __restrict__ inv, int* __restrict__ cnt)
{
    const int tid = threadIdx.x;

    // Per-block dtype detection on the first 512 bytes of the mask buffer.
    // int32 0/1 data never exceeds 1; byte-bool data's int32 view exceeds 1
    // with P=7/8 per word -> P(misdetect over 128 words) = (1/8)^128 ~ 0.
    __shared__ int s_u8;
    if (tid == 0) s_u8 = 0;
    __syncthreads();
    if (tid < 128 && (unsigned)((const int*)um_raw)[tid] > 1u) atomicOr(&s_u8, 1);
    __syncthreads();
    const int is_u8 = s_u8;
    if (blockIdx.x == 0 && tid == 0) cnt[4] = is_u8;   // for main_kernel

    const int cvl = cvl_p[0];
    const unsigned char* m8 = (const unsigned char*)um_raw;
    const int* m32 = (const int*)um_raw;

    int hits = 0, upd = 0, anyu = 0, maxp1 = 0;        // maxp1 = max(pos+1, 0)
    for (int i = blockIdx.x * 256 + tid; i < NBS; i += 256 * PREP_BLOCKS) {
        const int p = pos[i];
        const int um = is_u8 ? (m8[i] != 0) : (m32[i] != 0);
        const int b = i >> 12;                         // i / S, S = 4096
        hits += (p < cvl) ? 1 : 0;
        upd += um;
        anyu |= um;
        const int p1 = p + 1;
        maxp1 = p1 > maxp1 ? p1 : maxp1;
        if (um && (unsigned)p < (unsigned)MAXSEQ)
            inv[b * MAXSEQ + p] = i + 1;
    }
    for (int off = 32; off; off >>= 1) {
        hits += __shfl_down(hits, off);
        upd  += __shfl_down(upd, off);
        anyu |= __shfl_down(anyu, off);
        const int o = __shfl_down(maxp1, off);
        maxp1 = o > maxp1 ? o : maxp1;
    }
    if ((tid & 63) == 0) {
        atomicAdd(&cnt[0], hits);
        atomicAdd(&cnt[1], upd);
        atomicOr(&cnt[2], anyu);
        atomicMax(&cnt[3], maxp1);
    }
}

// Main kernel: block t owns k/v row t AND cache row t (same flat index since
// MAXSEQ==S). Gathered rows whose source IS the block's own cache row (true
// for pos=arange inputs) read ck/cv once and store to both outputs from
// registers. Scattered cache rows are written from the k/v registers of the
// scattering block; each input row is read from HBM exactly once.
__global__ __launch_bounds__(256) void main_kernel(
    const vf4* __restrict__ k, const vf4* __restrict__ v,
    const vf4* __restrict__ ck, const vf4* __restrict__ cv,
    const int* __restrict__ pos, const void* __restrict__ um_raw,
    const int* __restrict__ cvl_p, const int* __restrict__ inv,
    const int* __restrict__ cnt, vf4* __restrict__ out,
    float* __restrict__ scalars)
{
    const int t = blockIdx.x;
    const int tid = threadIdx.x;

    if (t == 0 && tid == 0) {   // finalize scalar outputs (cnt complete: prep done)
        const int h = cnt[0], u = cnt[1], au = cnt[2], mp1 = cnt[3];
        const float ema_h = 0.01f * (float)h;
        const float ema_m = 0.01f * ((float)NBS - (float)h);
        scalars[0] = ema_h / (ema_h + ema_m + 1e-8f);
        const int cvl0 = cvl_p[0];
        int hi = cvl0 > mp1 ? cvl0 : mp1;              // max(cvl, max_pos+1), mp1>=0, cvl>=0
        if (hi > MAXSEQ) hi = MAXSEQ;
        scalars[1] = (float)(au ? hi : cvl0);
        scalars[2] = (float)u;
    }

    const int p = pos[t];
    const int is_u8 = cnt[4];
    const int um = is_u8 ? (((const unsigned char*)um_raw)[t] != 0)
                         : (((const int*)um_raw)[t] != 0);
    const int cvl = cvl_p[0];
    const int b = t >> 12;
    const bool gather = (p < cvl) && !um;
    const bool scat = um && ((unsigned)p < (unsigned)MAXSEQ);
    const int pc = ((unsigned)p < (unsigned)MAXSEQ) ? p : 0;       // safe index
    const long long row  = (long long)t * VR;
    const long long crow = (long long)(b * MAXSEQ + pc) * VR;      // gather src / scatter dst
    const bool copyc = inv[t] == 0;                    // own cache row not scattered-into
    const bool reuse = gather && (crow == row);        // gather source == own cache row

    const vf4* sK = gather ? (ck + crow) : (k + row);
    const vf4* sV = gather ? (cv + crow) : (v + row);
    vf4* dK = out + row;                               // k_out
    vf4* dV = out + NK4 + row;                         // v_out
    vf4* xK = out + 2 * NK4 + crow;                    // scatter dest (if scat)
    vf4* xV = out + 3 * NK4 + crow;
    const vf4* csK = ck + row;                         // own cache row src
    const vf4* csV = cv + row;
    vf4* cdK = out + 2 * NK4 + row;                    // own cache row dest
    vf4* cdV = out + 3 * NK4 + row;

    #pragma unroll
    for (int i = tid; i < VR; i += 256) {
        const vf4 a = sK[i];
        const vf4 w = sV[i];
        __builtin_nontemporal_store(a, &dK[i]);
        __builtin_nontemporal_store(w, &dV[i]);
        if (scat) {
            __builtin_nontemporal_store(a, &xK[i]);
            __builtin_nontemporal_store(w, &xV[i]);
        }
        if (copyc) {
            const vf4 ca = reuse ? a : csK[i];
            const vf4 cw = reuse ? w : csV[i];
            __builtin_nontemporal_store(ca, &cdK[i]);
            __builtin_nontemporal_store(cw, &cdV[i]);
        }
    }
}

extern "C" void kernel_launch(void* const* d_in, const int* in_sizes, int n_in,
                              void* d_out, int out_size, void* d_ws, size_t ws_size,
                              hipStream_t stream) {
    const float* k  = (const float*)d_in[0];
    const float* v  = (const float*)d_in[1];
    const float* ck = (const float*)d_in[2];
    const float* cv = (const float*)d_in[3];
    const int* pos  = (const int*)d_in[4];
    const void* um  = d_in[5];
    const int* cvl  = (const int*)d_in[6];
    float* out = (float*)d_out;

    int* inv = (int*)d_ws;          // NCACHE ints
    int* cnt = inv + NCACHE;        // 8 ints

    hipMemsetAsync(d_ws, 0, (size_t)(NCACHE + 8) * sizeof(int), stream);
    prep_kernel<<<PREP_BLOCKS, 256, 0, stream>>>(pos, um, cvl, inv, cnt);
    main_kernel<<<NBS, 256, 0, stream>>>(
        (const vf4*)k, (const vf4*)v, (const vf4*)ck, (const vf4*)cv,
        pos, um, cvl, inv, cnt, (vf4*)out, out + 4 * NK);
}